// Round 9
// baseline (1982.821 us; speedup 1.0000x reference)
//
#include <hip/hip_runtime.h>
#include <hip/hip_bf16.h>

// Informer forward, MI355X. Round 9:
// (a) XOR-swizzled global_load_lds GEMM staging — round 8's unpadded tiles had 8-way
//     LDS bank conflicts on ds_read_b128 (row*64B stride alternates 2 bank-quads);
//     swizzle slot = kchunk ^ ((row>>1)&3) -> staging lk = ((lane&3)^((lane>>3)&3))*8,
//     frag col = (quad^((l15>>1)&3))*8 -> all 8 bank-quads hit 2x = conflict-free.
// (b) ln_off_k -> one wave per row, zero barriers (shuffle-only), grid rows/4.
// (c) bnstat1_k 32 -> 256 blocks (was a latency disaster at 12% occupancy).
// (d) fc_k -> wave per row, coalesced y loads, butterfly reduce.
// Retained: dtype sniffer, fused QKV, one-time transpose prologue, packed-key fattn.
// Round 8: passed, absmax 0.0117, 1922 us.
// B=16, LE=512, LD=256, D=512, H=8, dk=64, DFF=2048, NE=3, ND=2, TOPK=16.

#define DM 512
#define DK 64

using bf16 = __hip_bfloat16;
typedef short s8v __attribute__((ext_vector_type(8)));
typedef float f4v __attribute__((ext_vector_type(4)));

__device__ inline float b2f(bf16 x) { return __bfloat162float(x); }
__device__ inline float u2f(unsigned short u) { return __uint_as_float((unsigned)u << 16); }
__device__ inline short f2bs(float v) {
    bf16 h = __float2bfloat16(v);
    return *reinterpret_cast<short*>(&h);
}

// flag f: 1 = raw inputs are bf16, 0 = raw inputs are fp32. idx in ELEMENTS.
__device__ inline float ldw(const void* p, unsigned i, int f) {
    return f ? b2f(((const bf16*)p)[i]) : ((const float*)p)[i];
}

// order-preserving float->u32 (monotonic)
__device__ inline unsigned f2ord(float s) {
    unsigned u = __float_as_uint(s);
    return u ^ ((unsigned)((int)u >> 31) | 0x80000000u);
}

// async global->LDS, 16 B per lane; lds dst wave-uniform base, lane i -> base+16*i
__device__ inline void gl_lds16(const short* g, short* l) {
    __builtin_amdgcn_global_load_lds(
        (const __attribute__((address_space(1))) unsigned int*)g,
        (__attribute__((address_space(3))) unsigned int*)l,
        16, 0, 0);
}

// ---------------- dtype sniffer ----------------
__global__ __launch_bounds__(256) void sniff_k(const unsigned* __restrict__ x, int nwords,
                                               int* __restrict__ flag) {
    __shared__ int red[4];
    const int t = threadIdx.x;
    int c = 0;
    for (int i = t; i < nwords; i += 256) c += ((x[i] & 0x7F80u) == 0x3F80u) ? 1 : 0;
    #pragma unroll
    for (int o = 32; o > 0; o >>= 1) c += __shfl_down(c, o);
    __syncthreads();
    if ((t & 63) == 0) red[t >> 6] = c;
    __syncthreads();
    if (t == 0) flag[0] = (red[0] + red[1] + red[2] + red[3] > nwords / 20) ? 1 : 0;
}

// ---------------- embedding ----------------
__global__ __launch_bounds__(256) void embed_k(
    const void* __restrict__ xv, const void* __restrict__ vw, const void* __restrict__ vb,
    const void* __restrict__ xm, const void* __restrict__ mw, const void* __restrict__ mb,
    bf16* __restrict__ Out, int rows, int Cv, int Cm, const int* __restrict__ flagp)
{
    const int f = *flagp;
    int i = blockIdx.x * 256 + threadIdx.x;
    if (i >= rows * DM) return;
    const int r = i >> 9, d = i & 511;
    float acc = ldw(vb, d, f) + ldw(mb, d, f);
    for (int c = 0; c < Cv; ++c) acc += ldw(xv, r * Cv + c, f) * ldw(vw, c * DM + d, f);
    for (int c = 0; c < Cm; ++c) acc += ldw(xm, r * Cm + c, f) * ldw(mw, c * DM + d, f);
    Out[i] = __float2bfloat16(acc);
}

// ---------------- weight transpose: raw [K][N] -> bf16 [N][K]; z batches sub-mats ----------------
__global__ __launch_bounds__(256) void transp_k(
    const void* __restrict__ W, unsigned off, unsigned zstride, bf16* __restrict__ out,
    int K, int N, const int* __restrict__ flagp)
{
    __shared__ float tile[32][33];
    const int f = *flagp;
    const unsigned zo = blockIdx.z * zstride;
    const int t = threadIdx.x;
    const int tx = t & 31, ty = t >> 5;               // 32 x 8
    const int n0 = blockIdx.x * 32, k0 = blockIdx.y * 32;
    #pragma unroll
    for (int i = 0; i < 4; ++i)
        tile[ty + 8 * i][tx] = ldw(W, off + zo + (unsigned)(k0 + ty + 8 * i) * N + n0 + tx, f);
    __syncthreads();
    #pragma unroll
    for (int i = 0; i < 4; ++i)
        out[(size_t)zo + (size_t)(n0 + ty + 8 * i) * K + k0 + tx] = __float2bfloat16(tile[tx][ty + 8 * i]);
}

// ---------------- MFMA GEMM 128x128 (256 thr): C = A[M,K]@Wt[N,K]^T + bias ----------------
// global_load_lds staging with XOR slot swizzle (conflict-free b128 frag reads).
template<bool G3, bool RELU>
__global__ __launch_bounds__(256) void mgemm_k(
    const short* __restrict__ A, const int* __restrict__ ridx,
    const short* __restrict__ Wt,
    const void* __restrict__ bias, unsigned boff0,
    bf16* __restrict__ C, int M, int N, int K, int lda, int ldc,
    const int* __restrict__ flagp)
{
    __shared__ short As[128 * 32];
    __shared__ short Ws[128 * 32];
    const int t = threadIdx.x;
    const int bm = blockIdx.y * 128, bn = blockIdx.x * 128;
    const int lane = t & 63, wave = t >> 6;
    const int mbase = (wave >> 1) * 64, nbase = (wave & 1) * 64;
    const int l15 = lane & 15, quad = lane >> 4;
    const int lrow = lane >> 2;
    const int lk = ((lane & 3) ^ ((lane >> 3) & 3)) * 8;      // swizzled k-chunk
    const int fsw = (quad ^ ((l15 >> 1) & 3)) * 8;            // swizzled frag column

    f4v acc[4][4] = {};

    for (int k0 = 0; k0 < K; k0 += 32) {
        __syncthreads();
        #pragma unroll
        for (int j = 0; j < 2; ++j) {
            const int rb = wave * 32 + j * 16;
            const int row = bm + rb + lrow;
            const int rowc = row < M ? row : M - 1;
            const short* g;
            if (G3) {
                const int r = ridx[(k0 >> 9) * M + rowc];
                g = A + (size_t)r * lda + (k0 & 511) + lk;
            } else {
                g = A + (size_t)rowc * lda + k0 + lk;
            }
            gl_lds16(g, &As[rb * 32]);
        }
        #pragma unroll
        for (int j = 0; j < 2; ++j) {
            const int nb = wave * 32 + j * 16;
            gl_lds16(Wt + (size_t)(bn + nb + lrow) * K + k0 + lk, &Ws[nb * 32]);
        }
        __syncthreads();
        s8v af[4], bfv[4];
        #pragma unroll
        for (int i = 0; i < 4; ++i) {
            af[i]  = *(const s8v*)&As[(mbase + i * 16 + l15) * 32 + fsw];
            bfv[i] = *(const s8v*)&Ws[(nbase + i * 16 + l15) * 32 + fsw];
        }
        #pragma unroll
        for (int mi = 0; mi < 4; ++mi)
            #pragma unroll
            for (int ni = 0; ni < 4; ++ni)
                acc[mi][ni] = __builtin_amdgcn_mfma_f32_16x16x32_bf16(
                    af[mi], bfv[ni], acc[mi][ni], 0, 0, 0);
    }

    const int f = *flagp;
    float bv[4];
    #pragma unroll
    for (int ni = 0; ni < 4; ++ni)
        bv[ni] = ldw(bias, boff0 + (unsigned)(bn + nbase + ni * 16 + l15), f);

    #pragma unroll
    for (int mi = 0; mi < 4; ++mi) {
        #pragma unroll
        for (int r = 0; r < 4; ++r) {
            const int row = bm + mbase + mi * 16 + quad * 4 + r;
            if (row < M) {
                #pragma unroll
                for (int ni = 0; ni < 4; ++ni) {
                    float o = acc[mi][ni][r] + bv[ni];
                    if (RELU) o = fmaxf(o, 0.f);
                    C[(size_t)row * ldc + bn + nbase + ni * 16 + l15] = __float2bfloat16(o);
                }
            }
        }
    }
}

// ---------------- MFMA GEMM 128x64 (128 thr, 2 waves): for N=512-class GEMMs ----------------
template<bool G3, bool RELU>
__global__ __launch_bounds__(128) void mgemm64_k(
    const short* __restrict__ A, const int* __restrict__ ridx,
    const short* __restrict__ Wt,
    const void* __restrict__ bias, unsigned boff0,
    bf16* __restrict__ C, int M, int N, int K, int lda, int ldc,
    const int* __restrict__ flagp)
{
    __shared__ short As[128 * 32];
    __shared__ short Ws[64 * 32];
    const int t = threadIdx.x;
    const int bm = blockIdx.y * 128, bn = blockIdx.x * 64;
    const int lane = t & 63, wave = t >> 6;
    const int mbase = wave * 64;
    const int l15 = lane & 15, quad = lane >> 4;
    const int lrow = lane >> 2;
    const int lk = ((lane & 3) ^ ((lane >> 3) & 3)) * 8;
    const int fsw = (quad ^ ((l15 >> 1) & 3)) * 8;

    f4v acc[4][4] = {};

    for (int k0 = 0; k0 < K; k0 += 32) {
        __syncthreads();
        #pragma unroll
        for (int j = 0; j < 4; ++j) {
            const int rb = wave * 64 + j * 16;
            const int row = bm + rb + lrow;
            const int rowc = row < M ? row : M - 1;
            const short* g;
            if (G3) {
                const int r = ridx[(k0 >> 9) * M + rowc];
                g = A + (size_t)r * lda + (k0 & 511) + lk;
            } else {
                g = A + (size_t)rowc * lda + k0 + lk;
            }
            gl_lds16(g, &As[rb * 32]);
        }
        #pragma unroll
        for (int j = 0; j < 2; ++j) {
            const int nb = wave * 32 + j * 16;
            gl_lds16(Wt + (size_t)(bn + nb + lrow) * K + k0 + lk, &Ws[nb * 32]);
        }
        __syncthreads();
        s8v af[4], bfv[4];
        #pragma unroll
        for (int i = 0; i < 4; ++i) {
            af[i]  = *(const s8v*)&As[(mbase + i * 16 + l15) * 32 + fsw];
            bfv[i] = *(const s8v*)&Ws[(i * 16 + l15) * 32 + fsw];
        }
        #pragma unroll
        for (int mi = 0; mi < 4; ++mi)
            #pragma unroll
            for (int ni = 0; ni < 4; ++ni)
                acc[mi][ni] = __builtin_amdgcn_mfma_f32_16x16x32_bf16(
                    af[mi], bfv[ni], acc[mi][ni], 0, 0, 0);
    }

    const int f = *flagp;
    float bv[4];
    #pragma unroll
    for (int ni = 0; ni < 4; ++ni)
        bv[ni] = ldw(bias, boff0 + (unsigned)(bn + ni * 16 + l15), f);

    #pragma unroll
    for (int mi = 0; mi < 4; ++mi) {
        #pragma unroll
        for (int r = 0; r < 4; ++r) {
            const int row = bm + mbase + mi * 16 + quad * 4 + r;
            if (row < M) {
                #pragma unroll
                for (int ni = 0; ni < 4; ++ni) {
                    float o = acc[mi][ni][r] + bv[ni];
                    if (RELU) o = fmaxf(o, 0.f);
                    C[(size_t)row * ldc + bn + ni * 16 + l15] = __float2bfloat16(o);
                }
            }
        }
    }
}

// ---------------- fused tile attention (strided q/k/v) ----------------
// MODE 0: ProbSparse top-16. MODE 1: causal. MODE 2: plain cross.
template<int MODE>
__global__ __launch_bounds__(256) void fattn_k(
    bf16* __restrict__ q, const bf16* __restrict__ k, const bf16* __restrict__ v,
    int ldq, int ldkv, int Lq, int Lk)
{
    __shared__ short Qs[16 * 72];
    __shared__ short Ks[64 * 72];
    __shared__ float S[16 * 516];
    __shared__ float pw[16][16];
    __shared__ int   pidx[16][16];
    __shared__ float mrow[16];
    __shared__ float dinv[16];

    const int t = threadIdx.x;
    const int q0 = blockIdx.x * 16, h = blockIdx.y, b = blockIdx.z;
    const int lane = t & 63, wave = t >> 6;
    const int l15 = lane & 15, quad = lane >> 4;

    const int qv = (Lq - q0) < 16 ? (Lq - q0) : 16;

    const bf16* Kbase = k + (size_t)b * Lk * ldkv + h * DK;
    const bf16* Vbase = v + (size_t)b * Lk * ldkv + h * DK;
    bf16* Qbase = q + (size_t)(b * Lq + q0) * ldq + h * DK;

    const int kmax = (MODE == 1) ? (q0 + 16 < Lk ? q0 + 16 : Lk) : Lk;
    const int ntile = (kmax + 63) >> 6;
    const int kpad = ntile << 6;

    if (t < 128) {
        const int qr = t >> 3;
        const int qsrc = qr < qv ? qr : qv - 1;
        *(s8v*)&Qs[qr * 72 + (t & 7) * 8] =
            *(const s8v*)(Qbase + (size_t)qsrc * ldq + (t & 7) * 8);
    }

    // ---- phase 1: S = QK^T / 8 (+ masks), via MFMA ----
    for (int kt = 0; kt < ntile; ++kt) {
        __syncthreads();
        const int k0 = kt << 6;
        int srow = k0 + (t >> 2); if (srow >= Lk) srow = Lk - 1;
        const bf16* kp = Kbase + (size_t)srow * ldkv + (t & 3) * 16;
        *(s8v*)&Ks[(t >> 2) * 72 + (t & 3) * 16]     = *(const s8v*)kp;
        *(s8v*)&Ks[(t >> 2) * 72 + (t & 3) * 16 + 8] = *(const s8v*)(kp + 8);
        __syncthreads();
        const s8v a0 = *(const s8v*)&Qs[l15 * 72 + quad * 8];
        const s8v a1 = *(const s8v*)&Qs[l15 * 72 + 32 + quad * 8];
        const s8v b0 = *(const s8v*)&Ks[(wave * 16 + l15) * 72 + quad * 8];
        const s8v b1 = *(const s8v*)&Ks[(wave * 16 + l15) * 72 + 32 + quad * 8];
        f4v acc = {0.f, 0.f, 0.f, 0.f};
        acc = __builtin_amdgcn_mfma_f32_16x16x32_bf16(a0, b0, acc, 0, 0, 0);
        acc = __builtin_amdgcn_mfma_f32_16x16x32_bf16(a1, b1, acc, 0, 0, 0);
        const int colg = k0 + wave * 16 + l15;
        #pragma unroll
        for (int r = 0; r < 4; ++r) {
            const int qrow = quad * 4 + r;
            float s = acc[r] * 0.125f;
            if (colg >= Lk) s = -1e9f;
            if (MODE == 1 && colg > q0 + qrow) s = -1e9f;
            S[qrow * 516 + colg] = s;
        }
    }
    __syncthreads();

    // ---- phase 2 ----
    if (MODE == 0) {
        unsigned key[4][8];
        float mr[4], den[4];
        #pragma unroll
        for (int r = 0; r < 4; ++r) {
            const int row = wave * 4 + r;
            #pragma unroll
            for (int j = 0; j < 8; ++j) {
                const int col = lane + 64 * j;
                key[r][j] = (col < kpad)
                    ? ((f2ord(S[row * 516 + col]) & 0xFFFFFE00u) | (unsigned)col)
                    : 0u;
            }
            den[r] = 0.f;
            mr[r] = 0.f;
        }
        for (int it = 0; it < 16; ++it) {
            #pragma unroll
            for (int r = 0; r < 4; ++r) {
                unsigned mx = key[r][0];
                #pragma unroll
                for (int j = 1; j < 8; ++j) mx = mx > key[r][j] ? mx : key[r][j];
                #pragma unroll
                for (int off = 1; off < 64; off <<= 1) {
                    const unsigned o = __shfl_xor(mx, off);
                    mx = mx > o ? mx : o;
                }
                #pragma unroll
                for (int j = 0; j < 8; ++j) if (key[r][j] == mx) key[r][j] = 0u;
                const int col = (int)(mx & 511u);
                const int row = wave * 4 + r;
                const float sval = S[row * 516 + col];
                if (it == 0) mr[r] = sval;
                const float e = expf(sval - mr[r]);
                den[r] += e;
                if (lane == 0) { pw[row][it] = e; pidx[row][it] = col; }
            }
        }
        #pragma unroll
        for (int r = 0; r < 4; ++r)
            if (lane == 0) dinv[wave * 4 + r] = 1.f / den[r];
    } else {
        float mx[4];
        #pragma unroll
        for (int r = 0; r < 4; ++r) {
            const int row = wave * 4 + r;
            float lv = -INFINITY;
            #pragma unroll
            for (int j = 0; j < 8; ++j) {
                const int col = lane + 64 * j;
                if (col < kpad) lv = fmaxf(lv, S[row * 516 + col]);
            }
            mx[r] = lv;
        }
        #pragma unroll
        for (int off = 1; off < 64; off <<= 1) {
            #pragma unroll
            for (int r = 0; r < 4; ++r) mx[r] = fmaxf(mx[r], __shfl_xor(mx[r], off));
        }
        #pragma unroll
        for (int r = 0; r < 4; ++r)
            if (lane == 0) mrow[wave * 4 + r] = mx[r];
    }
    __syncthreads();

    const int row = t >> 4, c16 = t & 15;

    if (MODE != 0) {
        const float m = mrow[row];
        float part = 0.f;
        for (int j = 0; j < 32; ++j) {
            const int col = c16 + 16 * j;
            if (col < kpad) {
                const float w = expf(S[row * 516 + col] - m);
                S[row * 516 + col] = w;
                part += w;
            }
        }
        part += __shfl_xor(part, 1);
        part += __shfl_xor(part, 2);
        part += __shfl_xor(part, 4);
        part += __shfl_xor(part, 8);
        if (c16 == 0) dinv[row] = 1.f / part;
        __syncthreads();
    }

    // ---- phase 3: PV + store ----
    const float inv = dinv[row];
    float a0 = 0.f, a1 = 0.f, a2 = 0.f, a3 = 0.f;
    if (MODE == 0) {
        #pragma unroll
        for (int j = 0; j < 16; ++j) {
            const float w = pw[row][j];
            const int kk = pidx[row][j];
            const ushort4 u = *(const ushort4*)(Vbase + (size_t)kk * ldkv + c16 * 4);
            a0 += w * u2f(u.x); a1 += w * u2f(u.y);
            a2 += w * u2f(u.z); a3 += w * u2f(u.w);
        }
    } else {
        const int kend = (MODE == 1) ? (q0 + row + 1 < kmax ? q0 + row + 1 : kmax) : kmax;
        for (int k2 = 0; k2 < kend; ++k2) {
            const float w = S[row * 516 + k2];
            const ushort4 u = *(const ushort4*)(Vbase + (size_t)k2 * ldkv + c16 * 4);
            a0 += w * u2f(u.x); a1 += w * u2f(u.y);
            a2 += w * u2f(u.z); a3 += w * u2f(u.w);
        }
    }
    if (row < qv) {
        ushort4 o;
        { bf16 h0 = __float2bfloat16(a0 * inv); o.x = *(unsigned short*)&h0; }
        { bf16 h1 = __float2bfloat16(a1 * inv); o.y = *(unsigned short*)&h1; }
        { bf16 h2 = __float2bfloat16(a2 * inv); o.z = *(unsigned short*)&h2; }
        { bf16 h3 = __float2bfloat16(a3 * inv); o.w = *(unsigned short*)&h3; }
        *(ushort4*)(Qbase + (size_t)row * ldq + c16 * 4) = o;
    }
}

// ---------------- layernorm, one WAVE per row (no barriers, no LDS); grid = rows/4 ----------------
__global__ __launch_bounds__(256) void ln_off_k(
    const bf16* __restrict__ X, const bf16* __restrict__ R,
    const void* __restrict__ gb, unsigned goff,
    bf16* __restrict__ Out, const int* __restrict__ flagp)
{
    const int f = *flagp;
    const int lane = threadIdx.x & 63, wave = threadIdx.x >> 6;
    const size_t base = ((size_t)blockIdx.x * 4 + wave) * DM;
    const int d0 = lane * 8;

    const s8v x8 = *(const s8v*)(X + base + d0);
    float v[8];
    #pragma unroll
    for (int j = 0; j < 8; ++j) v[j] = u2f((unsigned short)x8[j]);
    if (R) {
        const s8v r8 = *(const s8v*)(R + base + d0);
        #pragma unroll
        for (int j = 0; j < 8; ++j) v[j] += u2f((unsigned short)r8[j]);
    }
    float s = 0.f;
    #pragma unroll
    for (int j = 0; j < 8; ++j) s += v[j];
    #pragma unroll
    for (int off = 1; off < 64; off <<= 1) s += __shfl_xor(s, off);
    const float mean = s * (1.f / 512.f);
    float qs = 0.f;
    #pragma unroll
    for (int j = 0; j < 8; ++j) { const float d = v[j] - mean; qs += d * d; }
    #pragma unroll
    for (int off = 1; off < 64; off <<= 1) qs += __shfl_xor(qs, off);
    const float rstd = rsqrtf(qs * (1.f / 512.f) + 1e-5f);

    s8v o;
    #pragma unroll
    for (int j = 0; j < 8; ++j)
        o[j] = f2bs((v[j] - mean) * rstd * ldw(gb, goff + d0 + j, f) + ldw(gb, goff + 512 + d0 + j, f));
    *(s8v*)(Out + base + d0) = o;
}

// ---------------- conv distill helpers ----------------
// conv weights w[2][o][c][j] -> transposed GEMM layout wt[layer][o][j*512+c]
__global__ __launch_bounds__(256) void convw_k(const void* __restrict__ w,
                                               bf16* __restrict__ wt, int total,
                                               const int* __restrict__ flagp) {
    const int f = *flagp;
    int i = blockIdx.x * 256 + threadIdx.x;
    if (i >= total) return;
    const int layer = i / 786432, rem2 = i % 786432;
    const int o = rem2 / 1536, rem = rem2 % 1536;
    const int j = rem >> 9, c = rem & 511;
    wt[i] = __float2bfloat16(ldw(w, (unsigned)layer * 786432u + (unsigned)(o * 512 + c) * 3 + j, f));
}

__global__ __launch_bounds__(256) void convidx_k(int* __restrict__ idx, int Lc, int L, int total) {
    int i = blockIdx.x * 256 + threadIdx.x;
    if (i >= total) return;
    const int j = i / (16 * Lc), mrem = i % (16 * Lc);
    const int b = mrem / Lc, l = mrem % Lc;
    int src = l + j - 2;
    src %= L; if (src < 0) src += L;
    idx[i] = b * L + src;
}

__global__ __launch_bounds__(256) void bnstat1_k(const bf16* __restrict__ Y, float* __restrict__ part, int M) {
    const int t = threadIdx.x;
    float s0 = 0.f, q0 = 0.f, s1 = 0.f, q1 = 0.f;
    for (int r = blockIdx.x; r < M; r += gridDim.x) {
        const ushort2 u = *reinterpret_cast<const ushort2*>(Y + (size_t)r * DM + t * 2);
        const float a = u2f(u.x), c = u2f(u.y);
        s0 += a; q0 += a * a;
        s1 += c; q1 += c * c;
    }
    float* p = part + (size_t)blockIdx.x * 1024;
    p[2 * t] = s0; p[2 * t + 1] = s1;
    p[512 + 2 * t] = q0; p[512 + 2 * t + 1] = q1;
}

__global__ __launch_bounds__(256) void bnstat2_k(const float* __restrict__ part, float* __restrict__ stats,
                                                 int nchunk, int M) {
    const int ch = blockIdx.x * 256 + threadIdx.x;
    if (ch >= 512) return;
    float S = 0.f, Qs = 0.f;
    for (int c = 0; c < nchunk; ++c) { S += part[c * 1024 + ch]; Qs += part[c * 1024 + 512 + ch]; }
    const float mean = S / (float)M;
    const float var = Qs / (float)M - mean * mean;
    stats[ch] = mean;
    stats[512 + ch] = fmaxf(var, 0.f);
}

__global__ __launch_bounds__(256) void bnpool_k(
    const bf16* __restrict__ Yc, const float* __restrict__ stats,
    const void* __restrict__ g, const void* __restrict__ bb, unsigned off,
    bf16* __restrict__ Out, int Lc, int Lout, int total, const int* __restrict__ flagp)
{
    const int f = *flagp;
    int i = blockIdx.x * 256 + threadIdx.x;
    if (i >= total) return;
    const int ch = i & 511;
    const int lp = (i >> 9) % Lout;
    const int b = i / (512 * Lout);
    const float mean = stats[ch], var = stats[512 + ch];
    const float sc = ldw(g, off + ch, f) * rsqrtf(var + 1e-5f);
    const float sh = ldw(bb, off + ch, f) - mean * sc;
    float mx = -INFINITY;
    const int l0 = 2 * lp - 1;
    #pragma unroll
    for (int d = 0; d < 3; ++d) {
        const int l = l0 + d;
        if (l >= 0 && l < Lc) {
            float vv = b2f(Yc[((size_t)b * Lc + l) * DM + ch]) * sc + sh;
            vv = vv > 0.f ? vv : expm1f(vv);  // ELU
            mx = fmaxf(mx, vv);
        }
    }
    Out[((size_t)b * Lout + lp) * DM + ch] = __float2bfloat16(mx);
}

// ---------------- final projection, one WAVE per row; grid = rows/4 ----------------
__global__ __launch_bounds__(256) void fc_k(
    const bf16* __restrict__ Yn, const void* __restrict__ fcw, const void* __restrict__ fcb,
    void* __restrict__ out, int rows, const int* __restrict__ flagp)
{
    const int f = *flagp;
    const int lane = threadIdx.x & 63, wave = threadIdx.x >> 6;
    const int r = blockIdx.x * 4 + wave;
    if (r >= rows) return;
    const int d0 = lane * 8;
    const s8v y8 = *(const s8v*)(Yn + (size_t)r * DM + d0);
    float y[8];
    #pragma unroll
    for (int j = 0; j < 8; ++j) y[j] = u2f((unsigned short)y8[j]);
    float acc[7] = {};
    #pragma unroll
    for (int j = 0; j < 8; ++j)
        #pragma unroll
        for (int co = 0; co < 7; ++co)
            acc[co] += y[j] * ldw(fcw, (unsigned)(d0 + j) * 7 + co, f);
    #pragma unroll
    for (int off = 1; off < 64; off <<= 1)
        #pragma unroll
        for (int co = 0; co < 7; ++co) acc[co] += __shfl_xor(acc[co], off);
    if (lane < 7) {
        const float o = acc[lane] + ldw(fcb, lane, f);
        if (f) ((bf16*)out)[r * 7 + lane] = __float2bfloat16(o);
        else   ((float*)out)[r * 7 + lane] = o;
    }
}

// =============================================================================
extern "C" void kernel_launch(void* const* d_in, const int* in_sizes, int n_in,
                              void* d_out, int out_size, void* d_ws, size_t ws_size,
                              hipStream_t stream)
{
    const void* x_enc      = d_in[0];
    const void* x_mark_enc = d_in[1];
    const void* x_dec      = d_in[2];
    const void* x_mark_dec = d_in[3];
    const void* enc_vw = d_in[4];
    const void* enc_vb = d_in[5];
    const void* enc_mw = d_in[6];
    const void* enc_mb = d_in[7];
    const void* dec_vw = d_in[8];
    const void* dec_vb = d_in[9];
    const void* dec_mw = d_in[10];
    const void* dec_mb = d_in[11];
    const void* eW    = d_in[12];
    const void* ebi   = d_in[13];
    const void* effw1 = d_in[14];
    const void* effb1 = d_in[15];
    const void* effw2 = d_in[16];
    const void* effb2 = d_in[17];
    const void* eln1  = d_in[18];
    const void* eln2  = d_in[19];
    const void* cw    = d_in[20];
    const void* cb    = d_in[21];
    const void* cbn_g = d_in[22];
    const void* cbn_b = d_in[23];
    const void* enc_norm = d_in[24];
    const void* dsW   = d_in[25];
    const void* dsb   = d_in[26];
    const void* dcW   = d_in[27];
    const void* dcb   = d_in[28];
    const void* dffw1 = d_in[29];
    const void* dffb1 = d_in[30];
    const void* dffw2 = d_in[31];
    const void* dffb2 = d_in[32];
    const void* dln   = d_in[33];
    const void* dec_norm = d_in[34];
    const void* fcw   = d_in[35];
    const void* fcb   = d_in[36];

    // ---- workspace layout (~91 MiB; 111 MiB footprint ran clean in round 1) ----
    char* wsp = (char*)d_ws;
    bf16* X    = (bf16*)wsp;
    bf16* QKV  = (bf16*)(wsp + ((size_t)8 << 20));
    bf16* HID  = QKV;                                 // FFN hidden aliases dead QKV
    bf16* OUT  = (bf16*)(wsp + ((size_t)40 << 20));
    bf16* WT   = (bf16*)(wsp + ((size_t)48 << 20));
    int*   IDX0 = (int*)(wsp + ((size_t)88 << 20));   // 3*16*514 ints
    int*   IDX1 = IDX0 + 24672;                       // 3*16*259 ints
    float* PART = (float*)(wsp + ((size_t)89 << 20)); // 256*1024 fp32 = 1 MiB
    float* STATS= (float*)(wsp + ((size_t)90 << 20));
    int*   FLAG = (int*)(wsp + ((size_t)90 << 20) + 8192);
    bf16* MEMb = X;                                               // [2080][512]
    bf16* Yd   = (bf16*)(wsp + (size_t)16 * 130 * 512 * 2);       // [4096][512]

    // transposed weight sub-arenas (element offsets)
    bf16* WTE  = WT;                    // enc QKVO: (i*4+q)*262144
    bf16* EW1T = WT + 3145728;
    bf16* EW2T = WT + 6291456;
    bf16* CWT  = WT + 9437184;
    bf16* DSWt = WT + 11010048;
    bf16* DCWt = WT + 13107200;
    bf16* DW1T = WT + 15204352;
    bf16* DW2T = WT + 17301504;

    auto cdiv = [](int a, int b) { return (a + b - 1) / b; };
    auto gemm = [&](const bf16* A, const bf16* Wt, const void* bias, unsigned boff,
                    bf16* C, int M, int N, int K, int lda, int ldc, bool relu) {
        dim3 g(N / 128, cdiv(M, 128));
        if (relu) mgemm_k<false, true><<<g, 256, 0, stream>>>(
            (const short*)A, nullptr, (const short*)Wt, bias, boff, C, M, N, K, lda, ldc, FLAG);
        else      mgemm_k<false, false><<<g, 256, 0, stream>>>(
            (const short*)A, nullptr, (const short*)Wt, bias, boff, C, M, N, K, lda, ldc, FLAG);
    };
    auto gemm64 = [&](const bf16* A, const bf16* Wt, const void* bias, unsigned boff,
                      bf16* C, int M, int N, int K, int lda, int ldc) {
        dim3 g(N / 64, cdiv(M, 128));
        mgemm64_k<false, false><<<g, 128, 0, stream>>>(
            (const short*)A, nullptr, (const short*)Wt, bias, boff, C, M, N, K, lda, ldc, FLAG);
    };
    auto transp = [&](const void* W, unsigned zstride, int nz, bf16* out, int K, int N) {
        transp_k<<<dim3(N / 32, K / 32, nz), 256, 0, stream>>>(W, 0u, zstride, out, K, N, FLAG);
    };
    auto ln = [&](const bf16* Xp, const bf16* Rp, const void* gb, unsigned goff,
                  bf16* Outp, int rows) {
        ln_off_k<<<rows / 4, 256, 0, stream>>>(Xp, Rp, gb, goff, Outp, FLAG);
    };

    // ---- prologue: sniff, all weight transposes, conv indices, embeddings ----
    sniff_k<<<1, 256, 0, stream>>>((const unsigned*)x_mark_enc, 16384, FLAG);
    transp(eW,    262144u, 12, WTE,  512, 512);
    transp(effw1, 1048576u, 3, EW1T, 512, 2048);
    transp(effw2, 1048576u, 3, EW2T, 2048, 512);
    convw_k<<<cdiv(1572864, 256), 256, 0, stream>>>(cw, CWT, 1572864, FLAG);
    transp(dsW,   262144u, 8, DSWt, 512, 512);
    transp(dcW,   262144u, 8, DCWt, 512, 512);
    transp(dffw1, 1048576u, 2, DW1T, 512, 2048);
    transp(dffw2, 1048576u, 2, DW2T, 2048, 512);
    convidx_k<<<cdiv(24672, 256), 256, 0, stream>>>(IDX0, 514, 512, 24672);
    convidx_k<<<cdiv(12432, 256), 256, 0, stream>>>(IDX1, 259, 257, 12432);
    embed_k<<<cdiv(16 * 512 * 512, 256), 256, 0, stream>>>(
        x_enc, enc_vw, enc_vb, x_mark_enc, enc_mw, enc_mb, X, 16 * 512, 7, 4, FLAG);

    // ---- encoder ----
    int L = 512;
    for (int i = 0; i < 3; ++i) {
        const int rows = 16 * L;
        const unsigned b0 = (unsigned)i * 4u * 512u;
        gemm(X, WTE + (size_t)i * 4 * 262144, ebi, b0, QKV, rows, 1536, 512, 512, 1536, false);
        fattn_k<0><<<dim3(cdiv(L, 16), 8, 16), 256, 0, stream>>>(
            QKV, QKV + 512, QKV + 1024, 1536, 1536, L, L);
        gemm64(QKV, WTE + (size_t)(i * 4 + 3) * 262144, ebi, b0 + 1536u, OUT, rows, 512, 512, 1536, 512);
        ln(X, OUT, eln1, (unsigned)i * 1024u, X, rows);

        gemm(X, EW1T + (size_t)i * 1048576, effb1, (unsigned)i * 2048u, HID, rows, 2048, 512, 512, 2048, true);
        gemm64(HID, EW2T + (size_t)i * 1048576, effb2, (unsigned)i * 512u, OUT, rows, 512, 2048, 2048, 512);
        ln(X, OUT, eln2, (unsigned)i * 1024u, X, rows);

        if (i < 2) {
            const int Lc = L + 2, Mc = 16 * Lc;
            const int* IDXi = (i == 0) ? IDX0 : IDX1;
            mgemm64_k<true, false><<<dim3(8, cdiv(Mc, 128)), 128, 0, stream>>>(
                (const short*)X, IDXi, (const short*)(CWT + (size_t)i * 786432),
                cb, (unsigned)i * 512u, QKV, Mc, 512, 1536, 512, 512, FLAG);
            bnstat1_k<<<256, 256, 0, stream>>>(QKV, PART, Mc);
            bnstat2_k<<<2, 256, 0, stream>>>(PART, STATS, 256, Mc);
            const int Lout = (L + 1) / 2 + 1;   // 514->257, 259->130
            const int tot = 16 * Lout * 512;
            bnpool_k<<<cdiv(tot, 256), 256, 0, stream>>>(
                QKV, STATS, cbn_g, cbn_b, (unsigned)i * 512u, X, Lc, Lout, tot, FLAG);
            L = Lout;
        }
    }
    const int Lm = L;  // 130
    ln(X, nullptr, enc_norm, 0u, MEMb, 16 * Lm);

    // ---- decoder embedding ----
    const int rowsD = 16 * 256;
    embed_k<<<cdiv(rowsD * 512, 256), 256, 0, stream>>>(
        x_dec, dec_vw, dec_vb, x_mark_dec, dec_mw, dec_mb, Yd, rowsD, 7, 4, FLAG);

    // ---- decoder ----
    bf16* CQ  = QKV;                       // [4096][512]
    bf16* CKV = QKV + (size_t)4096 * 512;  // [2080][1024]
    for (int i = 0; i < 2; ++i) {
        const unsigned b0 = (unsigned)i * 4u * 512u;
        // self-attention
        gemm(Yd, DSWt + (size_t)i * 4 * 262144, dsb, b0, QKV, rowsD, 1536, 512, 512, 1536, false);
        fattn_k<1><<<dim3(16, 8, 16), 256, 0, stream>>>(
            QKV, QKV + 512, QKV + 1024, 1536, 1536, 256, 256);
        gemm64(QKV, DSWt + (size_t)(i * 4 + 3) * 262144, dsb, b0 + 1536u, OUT, rowsD, 512, 512, 1536, 512);
        ln(Yd, OUT, dln, (unsigned)(i * 3 + 0) * 1024u, Yd, rowsD);

        // cross-attention
        gemm64(Yd, DCWt + (size_t)i * 4 * 262144, dcb, b0, CQ, rowsD, 512, 512, 512, 512);
        gemm(MEMb, DCWt + (size_t)(i * 4 + 1) * 262144, dcb, b0 + 512u, CKV, 16 * Lm, 1024, 512, 512, 1024, false);
        fattn_k<2><<<dim3(16, 8, 16), 256, 0, stream>>>(
            CQ, CKV, CKV + 512, 512, 1024, 256, Lm);
        gemm64(CQ, DCWt + (size_t)(i * 4 + 3) * 262144, dcb, b0 + 1536u, OUT, rowsD, 512, 512, 512, 512);
        ln(Yd, OUT, dln, (unsigned)(i * 3 + 1) * 1024u, Yd, rowsD);

        // FFN
        gemm(Yd, DW1T + (size_t)i * 1048576, dffb1, (unsigned)i * 2048u, HID, rowsD, 2048, 512, 512, 2048, true);
        gemm64(HID, DW2T + (size_t)i * 1048576, dffb2, (unsigned)i * 512u, OUT, rowsD, 512, 2048, 2048, 512);
        ln(Yd, OUT, dln, (unsigned)(i * 3 + 2) * 1024u, Yd, rowsD);
    }

    ln(Yd, nullptr, dec_norm, 0u, OUT, rowsD);
    fc_k<<<rowsD / 4, 256, 0, stream>>>(OUT, fcw, fcb, d_out, rowsD, FLAG);
}